// Round 11
// baseline (165.938 us; speedup 1.0000x reference)
//
#include <hip/hip_runtime.h>
#include <stdint.h>

typedef uint16_t u16;
typedef __attribute__((ext_vector_type(8))) short    bf16x8;  // 8 bf16 (4 VGPRs)
typedef __attribute__((ext_vector_type(8))) uint16_t u16x8;
typedef __attribute__((ext_vector_type(4))) float    f32x4;

#define B_    2
#define N_    100000
#define K_    26
#define CIN_  32
#define COUT_ 32
#define MID2  50000                                  // node-range split
#define ZROW  (N_ + 1)                               // all-zero dummy row (hot line)

#define XT_ROWS  (N_ + 2)                            // + fill row (N_), + zero row (N_+1)
#define XT_BYTES ((size_t)B_ * XT_ROWS * CIN_ * 2)

// ---- prep kernel geometry (xt [B][N+2][32] bf16 64B rows, Wb [32][832] bf16) ----
#define TCHUNK      64
#define TBLK_PER_B  ((N_ + TCHUNK - 1) / TCHUNK)     // 1563
#define TBLKS       (B_ * TBLK_PER_B)                // 3126
#define WBLKS       13                               // 13 * 2048 = 26624 W elems
#define PREP_GRID   (TBLKS + 1 + WBLKS)

// ---- conv kernel geometry ----
// 512-thr blocks, grid 768 = EXACTLY 3 blocks/CU (LDS 53,760B x3 = 161,280 ok),
// whole grid co-resident -> 2-pass phases stay chip-aligned (soft, via co-res +
// per-block __syncthreads at the pass boundary).
// Per batch: 384 blocks x 8 waves = 3072 waves; tiles 6250 = 2/wave + 106 tail.
#define CONV_GRID   768
#define WPB2        3072
#define TILES_PB    (N_ / 16)                        // 6250
#define TAIL        (TILES_PB - 2 * WPB2)            // 106
#define WPITCH      840                              // LDS W row pitch (2-way alias, free)

__device__ __forceinline__ u16 f2bf(float f) {
    union { float f; uint32_t u; } v; v.f = f;
    return (u16)((v.u + 0x7FFFu + ((v.u >> 16) & 1u)) >> 16);  // RNE
}

__global__ __launch_bounds__(256) void prep_kernel(
    const float* __restrict__ inp, const float* __restrict__ W,
    const float* __restrict__ fill, u16* __restrict__ xt, u16* __restrict__ Wb)
{
    int tid = threadIdx.x;
    int blk = blockIdx.x;
    if (blk >= TBLKS) {
        int job = blk - TBLKS;
        if (job == 0) {
            if (tid < 64) {                            // fill row at N_
                int b = tid >> 5, c = tid & 31;
                xt[((size_t)b * XT_ROWS + N_) * CIN_ + c] = f2bf(fill[c]);
            } else if (tid < 128) {                    // zero row at N_+1
                int t = tid - 64;
                int b = t >> 5, c = t & 31;
                xt[((size_t)b * XT_ROWS + ZROW) * CIN_ + c] = (u16)0;
            }
        } else {
            int base = (job - 1) * 2048 + tid * 8;    // exact: 13*2048 = 26624
            const float4* src = (const float4*)(W + base);
            float4 x = src[0], y = src[1];
            u16x8 o;
            o[0] = f2bf(x.x); o[1] = f2bf(x.y); o[2] = f2bf(x.z); o[3] = f2bf(x.w);
            o[4] = f2bf(y.x); o[5] = f2bf(y.y); o[6] = f2bf(y.z); o[7] = f2bf(y.w);
            *(u16x8*)(Wb + base) = o;
        }
        return;
    }
    __shared__ u16 tile[64][40];
    int b  = blk / TBLK_PER_B;
    int n0 = (blk % TBLK_PER_B) * TCHUNK;
    const float* inb = inp + (size_t)b * CIN_ * N_;
    #pragma unroll
    for (int it = 0; it < 8; ++it) {
        int idx = it * 256 + tid;
        int c = idx >> 6, n = idx & 63;
        if (n0 + n < N_) tile[n][c] = f2bf(inb[(size_t)c * N_ + n0 + n]);
    }
    __syncthreads();
    int n = tid >> 2, seg = tid & 3;
    if (n0 + n < N_) {
        u16x8 v = *(const u16x8*)&tile[n][seg * 8];
        *(u16x8*)(xt + ((size_t)b * XT_ROWS + n0 + n) * CIN_ + seg * 8) = v;
    }
}

#define MFMA16(a, b, c) __builtin_amdgcn_mfma_f32_16x16x32_bf16((a), (b), (c), 0, 0, 0)

// Gather + MFMA GEMM: node-range 2-pass (per-(batch,pass) slice 3.2MB -> XCD L2)
// + R8's issue engine: W in LDS (vmcnt counts ONLY gathers -> counted waits),
// 13-deep gather ring per tile per pass, masked lanes hit the hot ZERO row.
// A = W (o = lane&15) from LDS, B = feats (node = lane&15), 64B gather rows.
__global__ __launch_bounds__(512, 6) void conv_kernel(
    const u16* __restrict__ xt, const u16* __restrict__ Wb,
    const int* __restrict__ nbr, const float* __restrict__ bias,
    float* __restrict__ out)
{
    __shared__ u16 Wl[COUT_ * WPITCH];                // 53,760 B
    int tid = threadIdx.x;
    for (int i = tid; i < 3328; i += 512) {           // stage W: 3328 16B chunks
        int row = i / 104, c8 = i - row * 104;
        *(u16x8*)&Wl[row * WPITCH + c8 * 8] = *(const u16x8*)(Wb + row * 832 + c8 * 8);
    }
    __syncthreads();

    int bid  = blockIdx.x;
    int xcd  = bid & 7, slot = bid >> 3;              // slot 0..95
    int b    = xcd >> 2;                              // batch -> XCD half
    int wv   = tid >> 6, lane = tid & 63;
    int l15  = lane & 15, g = lane >> 4;
    int w    = (slot * 4 + (xcd & 3)) * 8 + wv;       // wave id in batch [0,3072)

    const u16* xg   = xt + (size_t)b * XT_ROWS * CIN_ + (g << 3);
    const int* nbb  = nbr + (size_t)b * N_ * K_;
    float*     outb = out + (size_t)b * COUT_ * N_;
    const u16* wl   = &Wl[l15 * WPITCH + (g << 3)];

    int t0 = w, t1 = w + WPB2;                        // both < 6144, always valid
    const int* qpA = nbb + ((size_t)t0 * 16 + l15) * K_;
    const int* qpB = nbb + ((size_t)t1 * 16 + l15) * K_;

    f32x4 acc[2][2];
    acc[0][0] = 0.0f; acc[0][1] = 0.0f; acc[1][0] = 0.0f; acc[1][1] = 0.0f;

    bf16x8 f[13];
    #pragma unroll
    for (int p = 0; p < 2; ++p) {                     // node-range pass
        #pragma unroll
        for (int j = 0; j < 2; ++j) {                 // tile within pass (static)
            const int* qp = j ? qpB : qpA;
            // ---- issue 13 masked gathers ----
            #pragma unroll
            for (int k = 0; k < 13; ++k) {
                int ix = qp[k];
                uint32_t ia = ((ix < MID2) == (p == 0)) ? (uint32_t)ix : (uint32_t)ZROW;
                f[k] = *(const bf16x8*)(xg + ((size_t)ia << 5));
            }
            __builtin_amdgcn_sched_barrier(0);        // pin issue block
            // ---- consume half 0, refill with half 1 (masked) ----
            #pragma unroll
            for (int k = 0; k < 13; ++k) {
                bf16x8 a0 = *(const bf16x8*)(wl + k * 32);
                bf16x8 a1 = *(const bf16x8*)(wl + 16 * WPITCH + k * 32);
                int ix = qp[13 + k];
                uint32_t ia = ((ix < MID2) == (p == 0)) ? (uint32_t)ix : (uint32_t)ZROW;
                acc[j][0] = MFMA16(a0, f[k], acc[j][0]);
                acc[j][1] = MFMA16(a1, f[k], acc[j][1]);
                f[k] = *(const bf16x8*)(xg + ((size_t)ia << 5));
            }
            __builtin_amdgcn_sched_barrier(0);
            // ---- consume half 1 ----
            #pragma unroll
            for (int k = 0; k < 13; ++k) {
                bf16x8 a0 = *(const bf16x8*)(wl + (13 + k) * 32);
                bf16x8 a1 = *(const bf16x8*)(wl + 16 * WPITCH + (13 + k) * 32);
                acc[j][0] = MFMA16(a0, f[k], acc[j][0]);
                acc[j][1] = MFMA16(a1, f[k], acc[j][1]);
            }
        }
        __syncthreads();                              // pass boundary (phase align)
    }

    // ---- epilogue: D col = l15 -> node, D row = g*4+r -> o ----
    #pragma unroll
    for (int j = 0; j < 2; ++j) {
        int node = (j ? t1 : t0) * 16 + l15;
        #pragma unroll
        for (int r = 0; r < 4; ++r) {
            outb[(size_t)(g * 4 + r) * N_ + node]      = acc[j][0][r] + bias[g * 4 + r];
            outb[(size_t)(g * 4 + r + 16) * N_ + node] = acc[j][1][r] + bias[g * 4 + r + 16];
        }
    }

    // ---- tail: 106 tiles per batch, single-pass (R8 style) ----
    if (w < TAIL) {
        int t = 2 * WPB2 + w;
        const int* qp = nbb + ((size_t)t * 16 + l15) * K_;
        f32x4 c0 = 0.0f, c1 = 0.0f;
        #pragma unroll
        for (int k = 0; k < 13; ++k)
            f[k] = *(const bf16x8*)(xg + ((size_t)(uint32_t)qp[k] << 5));
        __builtin_amdgcn_sched_barrier(0);
        #pragma unroll
        for (int k = 0; k < 13; ++k) {
            bf16x8 a0 = *(const bf16x8*)(wl + k * 32);
            bf16x8 a1 = *(const bf16x8*)(wl + 16 * WPITCH + k * 32);
            int qn = qp[13 + k];
            c0 = MFMA16(a0, f[k], c0);
            c1 = MFMA16(a1, f[k], c1);
            f[k] = *(const bf16x8*)(xg + ((size_t)(uint32_t)qn << 5));
        }
        __builtin_amdgcn_sched_barrier(0);
        #pragma unroll
        for (int k = 0; k < 13; ++k) {
            bf16x8 a0 = *(const bf16x8*)(wl + (13 + k) * 32);
            bf16x8 a1 = *(const bf16x8*)(wl + 16 * WPITCH + (13 + k) * 32);
            c0 = MFMA16(a0, f[k], c0);
            c1 = MFMA16(a1, f[k], c1);
        }
        int node = t * 16 + l15;
        #pragma unroll
        for (int r = 0; r < 4; ++r) {
            outb[(size_t)(g * 4 + r) * N_ + node]      = c0[r] + bias[g * 4 + r];
            outb[(size_t)(g * 4 + r + 16) * N_ + node] = c1[r] + bias[g * 4 + r + 16];
        }
    }
}

extern "C" void kernel_launch(void* const* d_in, const int* in_sizes, int n_in,
                              void* d_out, int out_size, void* d_ws, size_t ws_size,
                              hipStream_t stream) {
    (void)in_sizes; (void)n_in; (void)out_size; (void)ws_size;
    const float* inp  = (const float*)d_in[0];
    const int*   nbr  = (const int*)d_in[1];
    const float* W    = (const float*)d_in[2];
    const float* bias = (const float*)d_in[3];
    const float* fill = (const float*)d_in[4];
    float* out = (float*)d_out;

    u16* xt = (u16*)d_ws;                              // [B][N+2][32] bf16
    u16* Wb = (u16*)((char*)d_ws + XT_BYTES);          // [32][832] bf16

    prep_kernel<<<PREP_GRID, 256, 0, stream>>>(inp, W, fill, xt, Wb);
    conv_kernel<<<CONV_GRID, 512, 0, stream>>>(xt, Wb, nbr, bias, out);
}

// Round 12
// 83.301 us; speedup vs baseline: 1.9920x; 1.9920x over previous
//
#include <hip/hip_runtime.h>
#include <hip/hip_cooperative_groups.h>
#include <stdint.h>

namespace cg = cooperative_groups;

typedef uint16_t u16;
typedef __attribute__((ext_vector_type(8))) short    bf16x8;  // 8 bf16 (4 VGPRs)
typedef __attribute__((ext_vector_type(8))) uint16_t u16x8;
typedef __attribute__((ext_vector_type(4))) float    f32x4;

#define B_    2
#define N_    100000
#define K_    26
#define CIN_  32
#define COUT_ 32

#define XT_ROWS  (N_ + 1)
// xt2: [2][B][XT_ROWS][16] bf16 (32B rows); per (h,b) slice = 3.2MB < 4MB XCD L2
#define XT2_BYTES ((size_t)2 * B_ * XT_ROWS * 16 * 2)   // 12,800,128 bytes

// ---- prep kernel geometry (R4 layout, numerically verified) ----
#define TCHUNK      64
#define TBLK_PER_B  ((N_ + TCHUNK - 1) / TCHUNK)     // 1563
#define TBLKS       (B_ * TBLK_PER_B)                // 3126
#define WBLKS       13                               // 13*256 = 3328 8-elem chunks
#define PREP_GRID   (TBLKS + 1 + WBLKS)

// ---- conv kernel geometry ----
// Grid 512 x 512thr = EXACTLY 2 blocks/CU (LDS 67,072B x2 = 134,144 <= 163,840;
// VGPR <=128 via launch_bounds(512,4)) -> cooperative launch valid; grid.sync()
// gives HARD phase alignment so one 3.2MB slice is hot per XCD per phase.
// Per batch: 256 blocks x 8 waves = 2048 waves; 6250 tiles = 3/wave + 106 tail.
#define CONV_GRID   512
#define WPBATCH     2048
#define TILES_PB    (N_ / 16)                        // 6250
#define TAIL        (TILES_PB - 3 * WPBATCH)         // 106
#define WLP         424                              // W LDS row pitch (elems): 2-way alias only
#define WHALF       (COUT_ * 26 * 16)                // 13312 elems per W half

__device__ __forceinline__ u16 f2bf(float f) {
    union { float f; uint32_t u; } v; v.f = f;
    return (u16)((v.u + 0x7FFFu + ((v.u >> 16) & 1u)) >> 16);  // RNE
}

// Transpose inp [B][CIN][N] f32 -> xt2 [2][B][N+1][16] bf16 (32B rows),
// fill row at n==N, W -> Wb2 [2][32][26][16] bf16.
__global__ __launch_bounds__(256) void prep_kernel(
    const float* __restrict__ inp, const float* __restrict__ W,
    const float* __restrict__ fill, u16* __restrict__ xt2, u16* __restrict__ Wb2)
{
    int tid = threadIdx.x;
    int blk = blockIdx.x;
    if (blk >= TBLKS) {
        int job = blk - TBLKS;
        if (job == 0) {
            if (tid < 64) {
                int h = tid >> 5, b = (tid >> 4) & 1, c = tid & 15;
                xt2[((size_t)(h * B_ + b) * XT_ROWS + N_) * 16 + c] = f2bf(fill[h * 16 + c]);
            }
        } else {
            int i = (job - 1) * 256 + tid;            // 8-elem chunk; 3328 total
            int c8 = i & 1;
            int t  = i >> 1;
            int k  = t % 26;
            int t2 = t / 26;
            int o  = t2 & 31;
            int h  = t2 >> 5;
            const float* src = W + o * 832 + k * 32 + h * 16 + c8 * 8;  // 32B aligned
            float4 x = ((const float4*)src)[0], y = ((const float4*)src)[1];
            u16x8 v;
            v[0] = f2bf(x.x); v[1] = f2bf(x.y); v[2] = f2bf(x.z); v[3] = f2bf(x.w);
            v[4] = f2bf(y.x); v[5] = f2bf(y.y); v[6] = f2bf(y.z); v[7] = f2bf(y.w);
            *(u16x8*)(Wb2 + (size_t)i * 8) = v;
        }
        return;
    }
    __shared__ u16 tile[64][40];                      // pad: rows 80B
    int b  = blk / TBLK_PER_B;
    int n0 = (blk % TBLK_PER_B) * TCHUNK;
    const float* inb = inp + (size_t)b * CIN_ * N_;
    #pragma unroll
    for (int it = 0; it < 8; ++it) {
        int idx = it * 256 + tid;
        int c = idx >> 6, n = idx & 63;
        if (n0 + n < N_) tile[n][c] = f2bf(inb[(size_t)c * N_ + n0 + n]);
    }
    __syncthreads();
    int n = tid >> 2, seg = tid & 3;                  // seg: (h = seg>>1, c8 = seg&1)
    if (n0 + n < N_) {
        u16x8 v = *(const u16x8*)&tile[n][seg * 8];
        int h = seg >> 1, c8 = seg & 1;
        *(u16x8*)(xt2 + ((size_t)(h * B_ + b) * XT_ROWS + n0 + n) * 16 + c8 * 8) = v;
    }
}

#define MFMA16(a, b, c) __builtin_amdgcn_mfma_f32_16x16x32_bf16((a), (b), (c), 0, 0, 0)

// Channel-split two-phase gather+MFMA GEMM with HARD grid sync between phases.
// Phase h: gather 32B rows from xt2[h][b] (3.2MB, L2-resident per XCD after
// cold fill). In-loop VM ops = gathers ONLY (idx from LDS, W from LDS).
// K=32 MFMA step = 2 neighbours x 16ch; lane g -> (gsel = g>>1, c8 = g&1).
// A = W (o = lane&15), B = feats (node = lane&15). acc persists across phases.
template<bool COOP>
__global__ __launch_bounds__(512, 4) void conv_kernel(
    const u16* __restrict__ xt2, const u16* __restrict__ Wb2,
    const int* __restrict__ nbr, const float* __restrict__ bias,
    float* __restrict__ out)
{
    __shared__ u16 Wl[COUT_ * WLP];                   // 27,136 B (one W half, padded)
    __shared__ int idxl[8][3][416];                   // 39,936 B; total 67,072 B
    int tid = threadIdx.x, bid = blockIdx.x;
    int xcd = bid & 7, slot = bid >> 3;               // slot 0..63
    int b   = xcd >> 2;                               // batch -> XCD half
    int wv  = tid >> 6, lane = tid & 63;
    int l15 = lane & 15, g = lane >> 4;
    int gsel = g >> 1, c8 = g & 1;
    int w = (slot * 4 + (xcd & 3)) * 8 + wv;          // wave id in batch [0,2048)

    const int* nbb  = nbr + (size_t)b * N_ * K_;
    float*     outb = out + (size_t)b * COUT_ * N_;

    // ---- stage idx for 3 tiles into LDS (coalesced; read via lgkm in-loop) ----
    #pragma unroll
    for (int j = 0; j < 3; ++j) {
        const int* src = nbb + (size_t)(w + j * WPBATCH) * (16 * K_);
        int* dst = idxl[wv][j];
        #pragma unroll
        for (int r = 0; r < 7; ++r) {
            int i = r * 64 + lane;
            if (i < 416) dst[i] = src[i];
        }
    }
    // tail tile idx -> registers (held across both phases)
    bool hasT = (w < TAIL);                           // wave-uniform
    int idxT[13];
    if (hasT) {
        const int* qp = nbb + ((size_t)(3 * WPBATCH + w) * 16 + l15) * K_;
        #pragma unroll
        for (int k = 0; k < 13; ++k) idxT[k] = qp[2 * k + gsel];
    }
    __syncthreads();

    f32x4 acc[4][2];
    #pragma unroll
    for (int j = 0; j < 4; ++j) { acc[j][0] = 0.0f; acc[j][1] = 0.0f; }

    #pragma unroll 1
    for (int h = 0; h < 2; ++h) {
        // stage W half h into padded LDS (1664 16B chunks / 512 threads)
        {
            const u16* wsrc = Wb2 + (size_t)h * WHALF;
            for (int i = tid; i < 1664; i += 512) {
                int o = i / 52, rem = i - o * 52;     // 52 chunks = 416 elems/row
                *(u16x8*)&Wl[o * WLP + rem * 8] = *(const u16x8*)(wsrc + i * 8);
            }
        }
        __syncthreads();

        const u16* xg = xt2 + (size_t)(h * B_ + b) * XT_ROWS * 16 + (c8 << 3);
        const u16* wl = &Wl[l15 * WLP + (gsel << 4) + (c8 << 3)];

        #pragma unroll
        for (int j = 0; j < 3; ++j) {
            const int* ql = &idxl[wv][j][l15 * 26];
            bf16x8 f[13];
            #pragma unroll
            for (int k = 0; k < 13; ++k) {            // issue 13 gathers (VM = only these)
                int ix = ql[2 * k + gsel];            // lgkm, does not poison vmcnt
                f[k] = *(const bf16x8*)(xg + ((size_t)(uint32_t)ix << 4));
            }
            __builtin_amdgcn_sched_barrier(0);        // pin issue block above consumers
            #pragma unroll
            for (int k = 0; k < 13; ++k) {
                bf16x8 a0 = *(const bf16x8*)(wl + k * 32);
                bf16x8 a1 = *(const bf16x8*)(wl + 16 * WLP + k * 32);
                acc[j][0] = MFMA16(a0, f[k], acc[j][0]);
                acc[j][1] = MFMA16(a1, f[k], acc[j][1]);
            }
        }
        if (hasT) {
            bf16x8 f[13];
            #pragma unroll
            for (int k = 0; k < 13; ++k)
                f[k] = *(const bf16x8*)(xg + ((size_t)(uint32_t)idxT[k] << 4));
            __builtin_amdgcn_sched_barrier(0);
            #pragma unroll
            for (int k = 0; k < 13; ++k) {
                bf16x8 a0 = *(const bf16x8*)(wl + k * 32);
                bf16x8 a1 = *(const bf16x8*)(wl + 16 * WLP + k * 32);
                acc[3][0] = MFMA16(a0, f[k], acc[3][0]);
                acc[3][1] = MFMA16(a1, f[k], acc[3][1]);
            }
        }

        if (h == 0) {
            if constexpr (COOP) cg::this_grid().sync();   // HARD phase alignment
            else __syncthreads();                          // fallback: block-local only
        }
    }

    // ---- epilogue: D col = l15 -> node, D row = g*4+r -> o ----
    float bs0[4], bs1[4];
    #pragma unroll
    for (int r = 0; r < 4; ++r) {
        bs0[r] = bias[g * 4 + r];
        bs1[r] = bias[g * 4 + r + 16];
    }
    #pragma unroll
    for (int j = 0; j < 3; ++j) {
        int node = (w + j * WPBATCH) * 16 + l15;
        #pragma unroll
        for (int r = 0; r < 4; ++r) {
            outb[(size_t)(g * 4 + r) * N_ + node]      = acc[j][0][r] + bs0[r];
            outb[(size_t)(g * 4 + r + 16) * N_ + node] = acc[j][1][r] + bs1[r];
        }
    }
    if (hasT) {
        int node = (3 * WPBATCH + w) * 16 + l15;
        #pragma unroll
        for (int r = 0; r < 4; ++r) {
            outb[(size_t)(g * 4 + r) * N_ + node]      = acc[3][0][r] + bs0[r];
            outb[(size_t)(g * 4 + r + 16) * N_ + node] = acc[3][1][r] + bs1[r];
        }
    }
}

extern "C" void kernel_launch(void* const* d_in, const int* in_sizes, int n_in,
                              void* d_out, int out_size, void* d_ws, size_t ws_size,
                              hipStream_t stream) {
    (void)in_sizes; (void)n_in; (void)out_size; (void)ws_size;
    const float* inp  = (const float*)d_in[0];
    const int*   nbr  = (const int*)d_in[1];
    const float* W    = (const float*)d_in[2];
    const float* bias = (const float*)d_in[3];
    const float* fill = (const float*)d_in[4];
    float* out = (float*)d_out;

    u16* xt2 = (u16*)d_ws;                             // [2][B][N+1][16] bf16
    u16* Wb2 = (u16*)((char*)d_ws + XT2_BYTES);        // [2][32][26][16] bf16

    prep_kernel<<<PREP_GRID, 256, 0, stream>>>(inp, W, fill, xt2, Wb2);

    // cooperative launch (hard grid sync); fall back to non-coop variant if
    // the runtime/capture refuses it (fallback is correct, just slower).
    const u16* xt2a = xt2; const u16* Wb2a = Wb2;
    const int* nbra = nbr; const float* biasa = bias; float* outa = out;
    void* args[] = { (void*)&xt2a, (void*)&Wb2a, (void*)&nbra, (void*)&biasa, (void*)&outa };

    int maxb = 0;
    hipError_t oe = hipOccupancyMaxActiveBlocksPerMultiprocessor(
        &maxb, reinterpret_cast<const void*>(&conv_kernel<true>), 512, 0);
    hipError_t e = hipErrorUnknown;
    if (oe == hipSuccess && maxb * 256 >= CONV_GRID) {
        e = hipLaunchCooperativeKernel(
            reinterpret_cast<const void*>(&conv_kernel<true>),
            dim3(CONV_GRID), dim3(512), args, 0u, stream);
    }
    if (e != hipSuccess) {
        conv_kernel<false><<<CONV_GRID, 512, 0, stream>>>(xt2a, Wb2a, nbra, biasa, outa);
    }
}